// Round 1
// baseline (624.711 us; speedup 1.0000x reference)
//
#include <hip/hip_runtime.h>
#include <hip/hip_bf16.h>

#define Bsz 4
#define Lseq 2048
#define Dm 512
#define Hh 8
#define HD 64
#define KSPLIT 4
#define KTILE 64

// ---------------- Wvo fold: Wvo[h][c] = sum_d Wv[(h*64+d)*512 + c] * Wo[h*64+d]
__global__ void wvo_kernel(const float* __restrict__ Wv, const float* __restrict__ Wo,
                           float* __restrict__ Wvo) {
    int h = blockIdx.x >> 1;
    int c = (blockIdx.x & 1) * 256 + threadIdx.x;
    float acc = 0.f;
    #pragma unroll 8
    for (int d = 0; d < HD; ++d)
        acc += Wv[(size_t)(h * HD + d) * Dm + c] * Wo[h * HD + d];
    Wvo[h * Dm + c] = acc;
}

// ---------------- Projection GEMM: C[M,512] = A[M,512] @ W[512,512]^T  (NT, fp32)
// 64x64 tile, 256 threads, 4x4 register blocking, K-tile 32 staged transposed in LDS.
__global__ void proj_kernel(const float* __restrict__ A, const float* __restrict__ W,
                            float* __restrict__ C) {
    __shared__ float As[32][68];
    __shared__ float Ws[32][68];
    int tid = threadIdx.x;
    int tx = tid & 15, ty = tid >> 4;
    int row0 = blockIdx.y * 64, col0 = blockIdx.x * 64;
    float acc[4][4] = {};
    for (int kt = 0; kt < Dm; kt += 32) {
        __syncthreads();
        #pragma unroll
        for (int i = 0; i < 2; ++i) {
            int f4 = tid + i * 256;       // 0..511
            int r = f4 >> 3;              // 0..63
            int c = (f4 & 7) * 4;         // 0..28
            float4 av = *(const float4*)(A + (size_t)(row0 + r) * Dm + kt + c);
            As[c + 0][r] = av.x; As[c + 1][r] = av.y; As[c + 2][r] = av.z; As[c + 3][r] = av.w;
            float4 wv = *(const float4*)(W + (size_t)(col0 + r) * Dm + kt + c);
            Ws[c + 0][r] = wv.x; Ws[c + 1][r] = wv.y; Ws[c + 2][r] = wv.z; Ws[c + 3][r] = wv.w;
        }
        __syncthreads();
        #pragma unroll
        for (int kk = 0; kk < 32; ++kk) {
            float4 a = *(const float4*)&As[kk][ty * 4];
            float4 b = *(const float4*)&Ws[kk][tx * 4];
            float ar[4] = {a.x, a.y, a.z, a.w};
            float br[4] = {b.x, b.y, b.z, b.w};
            #pragma unroll
            for (int i = 0; i < 4; ++i)
                #pragma unroll
                for (int j = 0; j < 4; ++j)
                    acc[i][j] += ar[i] * br[j];
        }
    }
    #pragma unroll
    for (int i = 0; i < 4; ++i)
        #pragma unroll
        for (int j = 0; j < 4; ++j)
            C[(size_t)(row0 + ty * 4 + i) * Dm + col0 + tx * 4 + j] = acc[i][j];
}

// ---------------- vo[b][h][l] = hidden[b,l,:] . Wvo[h,:]
__global__ void vo_kernel(const float* __restrict__ hidden, const float* __restrict__ Wvo,
                          float* __restrict__ vo) {
    int bh = blockIdx.x;           // 0..31
    int b = bh >> 3, h = bh & 7;
    int l = blockIdx.y * 256 + threadIdx.x;
    __shared__ float w[Dm];
    for (int i = threadIdx.x; i < Dm; i += 256) w[i] = Wvo[h * Dm + i];
    __syncthreads();
    const float* hr = hidden + ((size_t)b * Lseq + l) * Dm;
    float a0 = 0.f, a1 = 0.f, a2 = 0.f, a3 = 0.f;
    #pragma unroll 8
    for (int c = 0; c < Dm; c += 4) {
        float4 v = *(const float4*)(hr + c);
        a0 += v.x * w[c]; a1 += v.y * w[c + 1]; a2 += v.z * w[c + 2]; a3 += v.w * w[c + 3];
    }
    vo[(size_t)bh * Lseq + l] = (a0 + a1) + (a2 + a3);
}

// ---------------- attention scalar-output: per q-row, Y = sum exp(s)*vo, Z = sum exp(s)
// one thread per q-row; K tile broadcast from LDS; fp64 accumulation; KSPLIT partials.
__global__ void attn_kernel(const float* __restrict__ Q, const float* __restrict__ K,
                            const float* __restrict__ vo,
                            double* __restrict__ Yp, double* __restrict__ Zp) {
    int tid = threadIdx.x;
    int qblk = blockIdx.x;         // 0..255
    int bh = qblk >> 3;            // 0..31
    int qc = qblk & 7;
    int b = bh >> 3, h = bh & 7;
    int l = qc * 256 + tid;
    const float* qrow = Q + ((size_t)(b * Lseq + l)) * Dm + h * HD;
    float qreg[HD];
    #pragma unroll
    for (int i = 0; i < 16; ++i) {
        float4 v = *(const float4*)(qrow + i * 4);
        qreg[i * 4 + 0] = v.x; qreg[i * 4 + 1] = v.y; qreg[i * 4 + 2] = v.z; qreg[i * 4 + 3] = v.w;
    }
    __shared__ float Ks[KTILE][HD];
    __shared__ float vos[KTILE];
    double Y = 0.0, Z = 0.0;
    int k0 = blockIdx.y * (Lseq / KSPLIT);
    for (int kt = k0; kt < k0 + Lseq / KSPLIT; kt += KTILE) {
        __syncthreads();
        #pragma unroll
        for (int i = 0; i < 4; ++i) {
            int f4 = tid + i * 256;
            int r = f4 >> 4;
            int c = (f4 & 15) * 4;
            *(float4*)&Ks[r][c] = *(const float4*)(K + ((size_t)(b * Lseq + kt + r)) * Dm + h * HD + c);
        }
        if (tid < KTILE) vos[tid] = vo[(size_t)bh * Lseq + kt + tid];
        __syncthreads();
        #pragma unroll 4
        for (int kk = 0; kk < KTILE; ++kk) {
            float a0 = 0.f, a1 = 0.f, a2 = 0.f, a3 = 0.f;
            #pragma unroll
            for (int d4 = 0; d4 < 16; ++d4) {
                float4 kv = *(const float4*)&Ks[kk][d4 * 4];
                a0 += qreg[d4 * 4 + 0] * kv.x;
                a1 += qreg[d4 * 4 + 1] * kv.y;
                a2 += qreg[d4 * 4 + 2] * kv.z;
                a3 += qreg[d4 * 4 + 3] * kv.w;
            }
            float s = ((a0 + a1) + (a2 + a3)) * 0.125f;
            float e = __expf(s);
            Y += (double)e * (double)vos[kk];
            Z += (double)e;
        }
    }
    size_t idx = ((size_t)bh * Lseq + l) * KSPLIT + blockIdx.y;
    Yp[idx] = Y; Zp[idx] = Z;
}

// ---------------- boundary logits -> hard bits (replicating reference fp path)
__global__ void blhard_kernel(const double* __restrict__ Yp, const double* __restrict__ Zp,
                              const float* __restrict__ u, int* __restrict__ hard) {
    int i = blockIdx.x * 256 + threadIdx.x;   // b*L + l
    int b = i >> 11, l = i & (Lseq - 1);
    float bl = 0.f;
    #pragma unroll
    for (int h = 0; h < Hh; ++h) {
        size_t base = (((size_t)(b * Hh + h)) * Lseq + l) * KSPLIT;
        double Y = 0.0, Z = 0.0;
        #pragma unroll
        for (int ks = 0; ks < KSPLIT; ++ks) { Y += Yp[base + ks]; Z += Zp[base + ks]; }
        bl += (float)(Y / Z);
    }
    float x = bl + 1.0f;                       // + boundary_scores (== 1 exactly)
    float probs = 1.0f / (1.0f + expf(-x));
    probs = fminf(fmaxf(probs, 0.0f), 1.0f);
    float pl = logf(probs) - log1pf(-probs);
    float un = u[i];
    float noise = logf(un) - log1pf(-un);
    float t = pl + noise;
    float soft = 1.0f / (1.0f + expf(-t));
    hard[i] = (soft > 0.5f) ? 1 : 0;
}

// ---------------- per-batch scan: segment starts/ends + boundary count
__global__ void scan_kernel(const int* __restrict__ hard, int* __restrict__ segstart,
                            int* __restrict__ segend, int* __restrict__ kcount) {
    int b = blockIdx.x;
    int tid = threadIdx.x;
    __shared__ int hs[Lseq];
    __shared__ int chunk[256];
    for (int i = tid; i < Lseq; i += 256) {
        segstart[b * Lseq + i] = 0;
        segend[b * Lseq + i] = 0;
    }
    int base = b * Lseq;
    int sum = 0;
    int loc[8];
    #pragma unroll
    for (int j = 0; j < 8; ++j) {
        int v = hard[base + tid * 8 + j];
        hs[tid * 8 + j] = v;
        loc[j] = sum;
        sum += v;
    }
    chunk[tid] = sum;
    __syncthreads();
    for (int off = 1; off < 256; off <<= 1) {
        int v = (tid >= off) ? chunk[tid - off] : 0;
        __syncthreads();
        chunk[tid] += v;
        __syncthreads();
    }
    int ebase = chunk[tid] - sum;  // exclusive prefix of chunks
    #pragma unroll
    for (int j = 0; j < 8; ++j) {
        int ll = tid * 8 + j;
        int id = ebase + loc[j];
        if (ll == 0 || hs[ll - 1] == 1) segstart[b * Lseq + id] = ll;
        if (ll == Lseq - 1 || hs[ll] == 1) segend[b * Lseq + id] = ll + 1;
    }
    if (tid == 255) kcount[b] = chunk[255];
}

// ---------------- pooled[b,s,d] = mean of hidden over segment range (0 if empty)
__global__ void pool_kernel(const float* __restrict__ hidden, const int* __restrict__ segstart,
                            const int* __restrict__ segend, float* __restrict__ out) {
    int i = blockIdx.x * 256 + threadIdx.x;     // < B*L*D = 2^22
    int d = i & (Dm - 1);
    int s = (i >> 9) & (Lseq - 1);
    int b = i >> 20;
    int st = segstart[b * Lseq + s];
    int en = segend[b * Lseq + s];
    int n = en - st;
    float acc = 0.f;
    for (int l = st; l < en; ++l)
        acc += hidden[((size_t)b * Lseq + l) * Dm + d];
    out[i] = (n > 0) ? acc / (float)n : 0.0f;
}

// ---------------- binomial log-prob loss
__global__ void loss_kernel(const int* __restrict__ kcount, float* __restrict__ out) {
    if (threadIdx.x == 0 && blockIdx.x == 0) {
        float n = (float)Lseq;
        float acc = 0.f;
        for (int b = 0; b < Bsz; ++b) {
            float k = (float)kcount[b];
            float lp = lgammaf(n + 1.0f) - lgammaf(k + 1.0f) - lgammaf(n - k + 1.0f)
                     + k * logf(0.2f) + (n - k) * log1pf(-0.2f);
            acc += lp;
        }
        out[(size_t)Bsz * Lseq * Dm] = -(acc / (float)Bsz) / n;
    }
}

extern "C" void kernel_launch(void* const* d_in, const int* in_sizes, int n_in,
                              void* d_out, int out_size, void* d_ws, size_t ws_size,
                              hipStream_t stream) {
    const float* hidden = (const float*)d_in[0];
    const float* Wq = (const float*)d_in[1];
    const float* Wk = (const float*)d_in[2];
    const float* Wv = (const float*)d_in[3];
    const float* Wo = (const float*)d_in[4];
    const float* u  = (const float*)d_in[5];
    float* out = (float*)d_out;

    char* ws = (char*)d_ws;
    size_t off = 0;
    float* Qb = (float*)(ws + off);  off += (size_t)Bsz * Lseq * Dm * 4;          // 16 MB
    float* Kb = (float*)(ws + off);  off += (size_t)Bsz * Lseq * Dm * 4;          // 16 MB
    float* Wvo = (float*)(ws + off); off += (size_t)Hh * Dm * 4;
    float* vo = (float*)(ws + off);  off += (size_t)Bsz * Hh * Lseq * 4;
    double* Yp = (double*)(ws + off); off += (size_t)Bsz * Hh * Lseq * KSPLIT * 8;
    double* Zp = (double*)(ws + off); off += (size_t)Bsz * Hh * Lseq * KSPLIT * 8;
    int* hard = (int*)(ws + off);    off += (size_t)Bsz * Lseq * 4;
    int* segstart = (int*)(ws + off); off += (size_t)Bsz * Lseq * 4;
    int* segend = (int*)(ws + off);  off += (size_t)Bsz * Lseq * 4;
    int* kcount = (int*)(ws + off);  off += 64;

    wvo_kernel<<<dim3(16), dim3(256), 0, stream>>>(Wv, Wo, Wvo);
    proj_kernel<<<dim3(Dm / 64, (Bsz * Lseq) / 64), dim3(256), 0, stream>>>(hidden, Wq, Qb);
    proj_kernel<<<dim3(Dm / 64, (Bsz * Lseq) / 64), dim3(256), 0, stream>>>(hidden, Wk, Kb);
    vo_kernel<<<dim3(Bsz * Hh, Lseq / 256), dim3(256), 0, stream>>>(hidden, Wvo, vo);
    attn_kernel<<<dim3((Bsz * Hh * Lseq) / 256, KSPLIT), dim3(256), 0, stream>>>(Qb, Kb, vo, Yp, Zp);
    blhard_kernel<<<dim3((Bsz * Lseq) / 256), dim3(256), 0, stream>>>(Yp, Zp, u, hard);
    scan_kernel<<<dim3(Bsz), dim3(256), 0, stream>>>(hard, segstart, segend, kcount);
    pool_kernel<<<dim3((Bsz * Lseq * Dm) / 256), dim3(256), 0, stream>>>(hidden, segstart, segend, out);
    loss_kernel<<<dim3(1), dim3(64), 0, stream>>>(kcount, out);
}

// Round 2
// 402.580 us; speedup vs baseline: 1.5518x; 1.5518x over previous
//
#include <hip/hip_runtime.h>
#include <hip/hip_bf16.h>

#define Bsz 4
#define Lseq 2048
#define Dm 512
#define Hh 8
#define HD 64

typedef __attribute__((ext_vector_type(8))) _Float16 f16x8;
typedef __attribute__((ext_vector_type(4))) float f32x4;

// ---------------- Wvo fold: Wvo[h][c] = sum_d Wv[(h*64+d)*512 + c] * Wo[h*64+d]
__global__ void wvo_kernel(const float* __restrict__ Wv, const float* __restrict__ Wo,
                           float* __restrict__ Wvo) {
    int h = blockIdx.x >> 1;
    int c = (blockIdx.x & 1) * 256 + threadIdx.x;
    float acc = 0.f;
    #pragma unroll 8
    for (int d = 0; d < HD; ++d)
        acc += Wv[(size_t)(h * HD + d) * Dm + c] * Wo[h * HD + d];
    Wvo[h * Dm + c] = acc;
}

// ---------------- Fused Q+K projection: fp32 math, epilogue emits f16 hi/lo planes.
// Q = hidden @ Wq^T, K = hidden @ Wk^T. lo plane stored scaled by 2^11.
__global__ void proj_qk_kernel(const float* __restrict__ A,
                               const float* __restrict__ Wq, const float* __restrict__ Wk,
                               _Float16* __restrict__ Qhp, _Float16* __restrict__ Qlp,
                               _Float16* __restrict__ Khp, _Float16* __restrict__ Klp) {
    __shared__ float As[32][68];
    __shared__ float Wqs[32][68];
    __shared__ float Wks[32][68];
    int tid = threadIdx.x;
    int tx = tid & 15, ty = tid >> 4;
    int row0 = blockIdx.y * 64, col0 = blockIdx.x * 64;
    float accq[4][4] = {}, acck[4][4] = {};
    for (int kt = 0; kt < Dm; kt += 32) {
        __syncthreads();
        #pragma unroll
        for (int i = 0; i < 2; ++i) {
            int f4 = tid + i * 256;       // 0..511
            int rr = f4 >> 3;             // 0..63
            int cc = (f4 & 7) * 4;        // 0..28
            float4 av = *(const float4*)(A + (size_t)(row0 + rr) * Dm + kt + cc);
            As[cc + 0][rr] = av.x; As[cc + 1][rr] = av.y; As[cc + 2][rr] = av.z; As[cc + 3][rr] = av.w;
            float4 qv = *(const float4*)(Wq + (size_t)(col0 + rr) * Dm + kt + cc);
            Wqs[cc + 0][rr] = qv.x; Wqs[cc + 1][rr] = qv.y; Wqs[cc + 2][rr] = qv.z; Wqs[cc + 3][rr] = qv.w;
            float4 kv = *(const float4*)(Wk + (size_t)(col0 + rr) * Dm + kt + cc);
            Wks[cc + 0][rr] = kv.x; Wks[cc + 1][rr] = kv.y; Wks[cc + 2][rr] = kv.z; Wks[cc + 3][rr] = kv.w;
        }
        __syncthreads();
        #pragma unroll
        for (int kk = 0; kk < 32; ++kk) {
            float4 a = *(const float4*)&As[kk][ty * 4];
            float4 bq = *(const float4*)&Wqs[kk][tx * 4];
            float4 bk = *(const float4*)&Wks[kk][tx * 4];
            float ar[4] = {a.x, a.y, a.z, a.w};
            float bqr[4] = {bq.x, bq.y, bq.z, bq.w};
            float bkr[4] = {bk.x, bk.y, bk.z, bk.w};
            #pragma unroll
            for (int i = 0; i < 4; ++i)
                #pragma unroll
                for (int j = 0; j < 4; ++j) {
                    accq[i][j] += ar[i] * bqr[j];
                    acck[i][j] += ar[i] * bkr[j];
                }
        }
    }
    #pragma unroll
    for (int i = 0; i < 4; ++i)
        #pragma unroll
        for (int j = 0; j < 4; ++j) {
            size_t idx = (size_t)(row0 + ty * 4 + i) * Dm + col0 + tx * 4 + j;
            float vq = accq[i][j];
            _Float16 qh = (_Float16)vq;
            float rq = vq - (float)qh;
            Qhp[idx] = qh;
            Qlp[idx] = (_Float16)(rq * 2048.0f);
            float vk = acck[i][j];
            _Float16 kh = (_Float16)vk;
            float rk = vk - (float)kh;
            Khp[idx] = kh;
            Klp[idx] = (_Float16)(rk * 2048.0f);
        }
}

// ---------------- vo[b][h][l] = hidden[b,l,:] . Wvo[h,:]
__global__ void vo_kernel(const float* __restrict__ hidden, const float* __restrict__ Wvo,
                          float* __restrict__ vo) {
    int bh = blockIdx.x;           // 0..31
    int b = bh >> 3, h = bh & 7;
    int l = blockIdx.y * 256 + threadIdx.x;
    __shared__ float w[Dm];
    for (int i = threadIdx.x; i < Dm; i += 256) w[i] = Wvo[h * Dm + i];
    __syncthreads();
    const float* hr = hidden + ((size_t)b * Lseq + l) * Dm;
    float a0 = 0.f, a1 = 0.f, a2 = 0.f, a3 = 0.f;
    #pragma unroll 8
    for (int c = 0; c < Dm; c += 4) {
        float4 v = *(const float4*)(hr + c);
        a0 += v.x * w[c]; a1 += v.y * w[c + 1]; a2 += v.z * w[c + 2]; a3 += v.w * w[c + 3];
    }
    vo[(size_t)bh * Lseq + l] = (a0 + a1) + (a2 + a3);
}

// ---------------- MFMA attention: per-wave 16 q-rows, swapped mfma(K,Q).
// s = hh + (hl + lh)/2048 (f16x3 fp32-emulation); Y/Z accumulated in fp64 per lane,
// shfl_xor(16,32) reduce at end. blpart[bh][q] = Y/Z per head.
__global__ void __launch_bounds__(256, 4) attn_mfma_kernel(
    const _Float16* __restrict__ Qhp, const _Float16* __restrict__ Qlp,
    const _Float16* __restrict__ Khp, const _Float16* __restrict__ Klp,
    const float* __restrict__ vo, float* __restrict__ blpart) {
    int tid = threadIdx.x;
    int wid = tid >> 6, lane = tid & 63;
    int blk = blockIdx.x;
    int bh = blk & 31;             // same-bh blocks land on same XCD (stride 32)
    int qblk = blk >> 5;           // 0..31
    int b = bh >> 3, h = bh & 7;
    int q0 = qblk * 64 + wid * 16;
    int r = lane & 15, g = lane >> 4;

    __shared__ float vos[Lseq];
    for (int i = tid; i < Lseq; i += 256) vos[i] = vo[(size_t)bh * Lseq + i];
    __syncthreads();

    // Q B-frags: col = q0+r, d = h*64 + chunk*32 + g*8 .. +7
    size_t qbase = ((size_t)(b * Lseq + q0 + r)) * Dm + h * HD + g * 8;
    f16x8 Qh0 = *(const f16x8*)(Qhp + qbase);
    f16x8 Qh1 = *(const f16x8*)(Qhp + qbase + 32);
    f16x8 Ql0 = *(const f16x8*)(Qlp + qbase);
    f16x8 Ql1 = *(const f16x8*)(Qlp + qbase + 32);

    size_t kbase = ((size_t)(b * Lseq + r)) * Dm + h * HD + g * 8;
    // prefetch tile 0
    f16x8 a_h0 = *(const f16x8*)(Khp + kbase);
    f16x8 a_h1 = *(const f16x8*)(Khp + kbase + 32);
    f16x8 a_l0 = *(const f16x8*)(Klp + kbase);
    f16x8 a_l1 = *(const f16x8*)(Klp + kbase + 32);

    double Y = 0.0, Z = 0.0;
    for (int kt = 0; kt < Lseq; kt += 16) {
        f16x8 h0 = a_h0, h1 = a_h1, l0 = a_l0, l1 = a_l1;
        if (kt + 16 < Lseq) {
            size_t nb = kbase + (size_t)(kt + 16) * Dm;
            a_h0 = *(const f16x8*)(Khp + nb);
            a_h1 = *(const f16x8*)(Khp + nb + 32);
            a_l0 = *(const f16x8*)(Klp + nb);
            a_l1 = *(const f16x8*)(Klp + nb + 32);
        }
        f32x4 acc1 = {0.f, 0.f, 0.f, 0.f};
        f32x4 acc2 = {0.f, 0.f, 0.f, 0.f};
        acc1 = __builtin_amdgcn_mfma_f32_16x16x32_f16(h0, Qh0, acc1, 0, 0, 0);
        acc1 = __builtin_amdgcn_mfma_f32_16x16x32_f16(h1, Qh1, acc1, 0, 0, 0);
        acc2 = __builtin_amdgcn_mfma_f32_16x16x32_f16(h0, Ql0, acc2, 0, 0, 0);
        acc2 = __builtin_amdgcn_mfma_f32_16x16x32_f16(h1, Ql1, acc2, 0, 0, 0);
        acc2 = __builtin_amdgcn_mfma_f32_16x16x32_f16(l0, Qh0, acc2, 0, 0, 0);
        acc2 = __builtin_amdgcn_mfma_f32_16x16x32_f16(l1, Qh1, acc2, 0, 0, 0);
        float e[4];
        float vk[4];
        #pragma unroll
        for (int j = 0; j < 4; ++j) {
            float s = (acc1[j] + acc2[j] * (1.0f / 2048.0f)) * 0.125f;
            e[j] = __expf(s);
            vk[j] = vos[kt + g * 4 + j];
        }
        float Ych = (e[0] * vk[0] + e[1] * vk[1]) + (e[2] * vk[2] + e[3] * vk[3]);
        float Zch = (e[0] + e[1]) + (e[2] + e[3]);
        Y += (double)Ych;
        Z += (double)Zch;
    }
    // reduce partials across the 4 row-groups (same q column)
    Y += __shfl_xor(Y, 16, 64);
    Y += __shfl_xor(Y, 32, 64);
    Z += __shfl_xor(Z, 16, 64);
    Z += __shfl_xor(Z, 32, 64);
    if (lane < 16)
        blpart[(size_t)bh * Lseq + q0 + lane] = (float)(Y / Z);
}

// ---------------- boundary logits -> hard bits (replicating reference fp path)
__global__ void blhard_kernel(const float* __restrict__ blpart, const float* __restrict__ u,
                              int* __restrict__ hard) {
    int i = blockIdx.x * 256 + threadIdx.x;   // b*L + l
    int b = i >> 11, l = i & (Lseq - 1);
    float bl = 0.f;
    #pragma unroll
    for (int h = 0; h < Hh; ++h)
        bl += blpart[((size_t)(b * Hh + h)) * Lseq + l];
    float x = bl + 1.0f;                       // + boundary_scores (== 1 exactly)
    float probs = 1.0f / (1.0f + expf(-x));
    probs = fminf(fmaxf(probs, 0.0f), 1.0f);
    float pl = logf(probs) - log1pf(-probs);
    float un = u[i];
    float noise = logf(un) - log1pf(-un);
    float t = pl + noise;
    float soft = 1.0f / (1.0f + expf(-t));
    hard[i] = (soft > 0.5f) ? 1 : 0;
}

// ---------------- per-batch scan: segment starts/ends + boundary count
__global__ void scan_kernel(const int* __restrict__ hard, int* __restrict__ segstart,
                            int* __restrict__ segend, int* __restrict__ kcount) {
    int b = blockIdx.x;
    int tid = threadIdx.x;
    __shared__ int hs[Lseq];
    __shared__ int chunk[256];
    for (int i = tid; i < Lseq; i += 256) {
        segstart[b * Lseq + i] = 0;
        segend[b * Lseq + i] = 0;
    }
    int base = b * Lseq;
    int sum = 0;
    int loc[8];
    #pragma unroll
    for (int j = 0; j < 8; ++j) {
        int v = hard[base + tid * 8 + j];
        hs[tid * 8 + j] = v;
        loc[j] = sum;
        sum += v;
    }
    chunk[tid] = sum;
    __syncthreads();
    for (int off = 1; off < 256; off <<= 1) {
        int v = (tid >= off) ? chunk[tid - off] : 0;
        __syncthreads();
        chunk[tid] += v;
        __syncthreads();
    }
    int ebase = chunk[tid] - sum;  // exclusive prefix of chunks
    #pragma unroll
    for (int j = 0; j < 8; ++j) {
        int ll = tid * 8 + j;
        int id = ebase + loc[j];
        if (ll == 0 || hs[ll - 1] == 1) segstart[b * Lseq + id] = ll;
        if (ll == Lseq - 1 || hs[ll] == 1) segend[b * Lseq + id] = ll + 1;
    }
    if (tid == 255) kcount[b] = chunk[255];
}

// ---------------- pooled[b,s,d] = mean of hidden over segment range (0 if empty)
__global__ void pool_kernel(const float* __restrict__ hidden, const int* __restrict__ segstart,
                            const int* __restrict__ segend, float* __restrict__ out) {
    int i = blockIdx.x * 256 + threadIdx.x;     // < B*L*D = 2^22
    int d = i & (Dm - 1);
    int s = (i >> 9) & (Lseq - 1);
    int b = i >> 20;
    int st = segstart[b * Lseq + s];
    int en = segend[b * Lseq + s];
    int n = en - st;
    float acc = 0.f;
    for (int l = st; l < en; ++l)
        acc += hidden[((size_t)b * Lseq + l) * Dm + d];
    out[i] = (n > 0) ? acc / (float)n : 0.0f;
}

// ---------------- binomial log-prob loss
__global__ void loss_kernel(const int* __restrict__ kcount, float* __restrict__ out) {
    if (threadIdx.x == 0 && blockIdx.x == 0) {
        float n = (float)Lseq;
        float acc = 0.f;
        for (int b = 0; b < Bsz; ++b) {
            float k = (float)kcount[b];
            float lp = lgammaf(n + 1.0f) - lgammaf(k + 1.0f) - lgammaf(n - k + 1.0f)
                     + k * logf(0.2f) + (n - k) * log1pf(-0.2f);
            acc += lp;
        }
        out[(size_t)Bsz * Lseq * Dm] = -(acc / (float)Bsz) / n;
    }
}

extern "C" void kernel_launch(void* const* d_in, const int* in_sizes, int n_in,
                              void* d_out, int out_size, void* d_ws, size_t ws_size,
                              hipStream_t stream) {
    const float* hidden = (const float*)d_in[0];
    const float* Wq = (const float*)d_in[1];
    const float* Wk = (const float*)d_in[2];
    const float* Wv = (const float*)d_in[3];
    const float* Wo = (const float*)d_in[4];
    const float* u  = (const float*)d_in[5];
    float* out = (float*)d_out;

    char* ws = (char*)d_ws;
    size_t off = 0;
    const size_t plane = (size_t)Bsz * Lseq * Dm * sizeof(_Float16);   // 8 MB
    _Float16* Qhp = (_Float16*)(ws + off); off += plane;
    _Float16* Qlp = (_Float16*)(ws + off); off += plane;
    _Float16* Khp = (_Float16*)(ws + off); off += plane;
    _Float16* Klp = (_Float16*)(ws + off); off += plane;
    float* Wvo = (float*)(ws + off); off += (size_t)Hh * Dm * 4;
    float* vo = (float*)(ws + off);  off += (size_t)Bsz * Hh * Lseq * 4;
    float* blpart = (float*)(ws + off); off += (size_t)Bsz * Hh * Lseq * 4;
    int* hard = (int*)(ws + off);    off += (size_t)Bsz * Lseq * 4;
    int* segstart = (int*)(ws + off); off += (size_t)Bsz * Lseq * 4;
    int* segend = (int*)(ws + off);  off += (size_t)Bsz * Lseq * 4;
    int* kcount = (int*)(ws + off);  off += 64;

    wvo_kernel<<<dim3(16), dim3(256), 0, stream>>>(Wv, Wo, Wvo);
    proj_qk_kernel<<<dim3(Dm / 64, (Bsz * Lseq) / 64), dim3(256), 0, stream>>>(
        hidden, Wq, Wk, Qhp, Qlp, Khp, Klp);
    vo_kernel<<<dim3(Bsz * Hh, Lseq / 256), dim3(256), 0, stream>>>(hidden, Wvo, vo);
    attn_mfma_kernel<<<dim3(32 * (Lseq / 64)), dim3(256), 0, stream>>>(
        Qhp, Qlp, Khp, Klp, vo, blpart);
    blhard_kernel<<<dim3((Bsz * Lseq) / 256), dim3(256), 0, stream>>>(blpart, u, hard);
    scan_kernel<<<dim3(Bsz), dim3(256), 0, stream>>>(hard, segstart, segend, kcount);
    pool_kernel<<<dim3((Bsz * Lseq * Dm) / 256), dim3(256), 0, stream>>>(hidden, segstart, segend, out);
    loss_kernel<<<dim3(1), dim3(64), 0, stream>>>(kcount, out);
}

// Round 3
// 245.344 us; speedup vs baseline: 2.5463x; 1.6409x over previous
//
#include <hip/hip_runtime.h>
#include <hip/hip_bf16.h>

#define Bsz 4
#define Lseq 2048
#define Dm 512
#define Hh 8
#define HD 64
#define QBLK 128
#define KT 64
#define NT (Lseq / KT)

typedef __attribute__((ext_vector_type(8))) _Float16 f16x8;
typedef __attribute__((ext_vector_type(4))) float f32x4;

// ---------------- Wvo fold: Wvo[h][c] = sum_d Wv[(h*64+d)*512 + c] * Wo[h*64+d]
__global__ void wvo_kernel(const float* __restrict__ Wv, const float* __restrict__ Wo,
                           float* __restrict__ Wvo) {
    int h = blockIdx.x >> 1;
    int c = (blockIdx.x & 1) * 256 + threadIdx.x;
    float acc = 0.f;
    #pragma unroll 8
    for (int d = 0; d < HD; ++d)
        acc += Wv[(size_t)(h * HD + d) * Dm + c] * Wo[h * HD + d];
    Wvo[h * Dm + c] = acc;
}

// ---------------- Fused Q+K projection: fp32 math, epilogue emits f16 hi/lo planes.
__global__ void proj_qk_kernel(const float* __restrict__ A,
                               const float* __restrict__ Wq, const float* __restrict__ Wk,
                               _Float16* __restrict__ Qhp, _Float16* __restrict__ Qlp,
                               _Float16* __restrict__ Khp, _Float16* __restrict__ Klp) {
    __shared__ float As[32][68];
    __shared__ float Wqs[32][68];
    __shared__ float Wks[32][68];
    int tid = threadIdx.x;
    int tx = tid & 15, ty = tid >> 4;
    int row0 = blockIdx.y * 64, col0 = blockIdx.x * 64;
    float accq[4][4] = {}, acck[4][4] = {};
    for (int kt = 0; kt < Dm; kt += 32) {
        __syncthreads();
        #pragma unroll
        for (int i = 0; i < 2; ++i) {
            int f4 = tid + i * 256;       // 0..511
            int rr = f4 >> 3;             // 0..63
            int cc = (f4 & 7) * 4;        // 0..28
            float4 av = *(const float4*)(A + (size_t)(row0 + rr) * Dm + kt + cc);
            As[cc + 0][rr] = av.x; As[cc + 1][rr] = av.y; As[cc + 2][rr] = av.z; As[cc + 3][rr] = av.w;
            float4 qv = *(const float4*)(Wq + (size_t)(col0 + rr) * Dm + kt + cc);
            Wqs[cc + 0][rr] = qv.x; Wqs[cc + 1][rr] = qv.y; Wqs[cc + 2][rr] = qv.z; Wqs[cc + 3][rr] = qv.w;
            float4 kv = *(const float4*)(Wk + (size_t)(col0 + rr) * Dm + kt + cc);
            Wks[cc + 0][rr] = kv.x; Wks[cc + 1][rr] = kv.y; Wks[cc + 2][rr] = kv.z; Wks[cc + 3][rr] = kv.w;
        }
        __syncthreads();
        #pragma unroll
        for (int kk = 0; kk < 32; ++kk) {
            float4 a = *(const float4*)&As[kk][ty * 4];
            float4 bq = *(const float4*)&Wqs[kk][tx * 4];
            float4 bk = *(const float4*)&Wks[kk][tx * 4];
            float ar[4] = {a.x, a.y, a.z, a.w};
            float bqr[4] = {bq.x, bq.y, bq.z, bq.w};
            float bkr[4] = {bk.x, bk.y, bk.z, bk.w};
            #pragma unroll
            for (int i = 0; i < 4; ++i)
                #pragma unroll
                for (int j = 0; j < 4; ++j) {
                    accq[i][j] += ar[i] * bqr[j];
                    acck[i][j] += ar[i] * bkr[j];
                }
        }
    }
    #pragma unroll
    for (int i = 0; i < 4; ++i)
        #pragma unroll
        for (int j = 0; j < 4; ++j) {
            size_t idx = (size_t)(row0 + ty * 4 + i) * Dm + col0 + tx * 4 + j;
            float vq = accq[i][j];
            _Float16 qh = (_Float16)vq;
            float rq = vq - (float)qh;
            Qhp[idx] = qh;
            Qlp[idx] = (_Float16)(rq * 2048.0f);
            float vk = acck[i][j];
            _Float16 kh = (_Float16)vk;
            float rk = vk - (float)kh;
            Khp[idx] = kh;
            Klp[idx] = (_Float16)(rk * 2048.0f);
        }
}

// ---------------- vo[b][h][l] = hidden[b,l,:] . Wvo[h,:]
__global__ void vo_kernel(const float* __restrict__ hidden, const float* __restrict__ Wvo,
                          float* __restrict__ vo) {
    int bh = blockIdx.x;           // 0..31
    int b = bh >> 3, h = bh & 7;
    int l = blockIdx.y * 256 + threadIdx.x;
    __shared__ float w[Dm];
    for (int i = threadIdx.x; i < Dm; i += 256) w[i] = Wvo[h * Dm + i];
    __syncthreads();
    const float* hr = hidden + ((size_t)b * Lseq + l) * Dm;
    float a0 = 0.f, a1 = 0.f, a2 = 0.f, a3 = 0.f;
    #pragma unroll 8
    for (int c = 0; c < Dm; c += 4) {
        float4 v = *(const float4*)(hr + c);
        a0 += v.x * w[c]; a1 += v.y * w[c + 1]; a2 += v.z * w[c + 2]; a3 += v.w * w[c + 3];
    }
    vo[(size_t)bh * Lseq + l] = (a0 + a1) + (a2 + a3);
}

// ---------------- MFMA attention, LDS-shared double-buffered K tiles.
// Block: 4 waves x 32 q-rows = 128 q-rows for one (b,h). K tile: KT=64 rows,
// hi+lo planes (64x64 halves each), XOR-swizzled (half_idx ^= (row&7)<<3).
// s = hh + (hl + lh)/2048; per-lane fp64 Y/Z accum, shfl_xor(16,32) reduce.
__global__ void __launch_bounds__(256, 2) attn_mfma_kernel(
    const _Float16* __restrict__ Qhp, const _Float16* __restrict__ Qlp,
    const _Float16* __restrict__ Khp, const _Float16* __restrict__ Klp,
    const float* __restrict__ vo, float* __restrict__ blpart) {
    int tid = threadIdx.x;
    int wid = tid >> 6, lane = tid & 63;
    int blk = blockIdx.x;
    int bh = blk & 31;             // same-bh blocks -> same XCD (blk%8 = bh%8)
    int qblk = blk >> 5;           // 0..15
    int b = bh >> 3, h = bh & 7;
    int q0 = qblk * QBLK + wid * 32;
    int r = lane & 15, g = lane >> 4;

    __shared__ _Float16 KhS[2][KT][64];
    __shared__ _Float16 KlS[2][KT][64];
    __shared__ float vos[Lseq];

    const _Float16* Kh_g = Khp + ((size_t)b * Lseq) * Dm + h * HD;
    const _Float16* Kl_g = Klp + ((size_t)b * Lseq) * Dm + h * HD;

    // staging coords: 512 16B-chunks per plane, 2 per thread
    int c0 = tid * 2, c1 = tid * 2 + 1;
    int sr0 = c0 >> 3, so0 = (c0 & 7) * 8;
    int sr1 = c1 >> 3, so1 = (c1 & 7) * 8;
    int dw0 = (so0 ^ ((sr0 & 7) << 3));
    int dw1 = (so1 ^ ((sr1 & 7) << 3));

    // prologue: issue tile-0 loads
    f16x8 nh0 = *(const f16x8*)(Kh_g + (size_t)sr0 * Dm + so0);
    f16x8 nh1 = *(const f16x8*)(Kh_g + (size_t)sr1 * Dm + so1);
    f16x8 nl0 = *(const f16x8*)(Kl_g + (size_t)sr0 * Dm + so0);
    f16x8 nl1 = *(const f16x8*)(Kl_g + (size_t)sr1 * Dm + so1);

    // Q fragments (2 per wave)
    f16x8 Qh[2][2], Ql[2][2];
    #pragma unroll
    for (int f = 0; f < 2; ++f) {
        size_t qbase = ((size_t)(b * Lseq + q0 + f * 16 + r)) * Dm + h * HD + g * 8;
        Qh[f][0] = *(const f16x8*)(Qhp + qbase);
        Qh[f][1] = *(const f16x8*)(Qhp + qbase + 32);
        Ql[f][0] = *(const f16x8*)(Qlp + qbase);
        Ql[f][1] = *(const f16x8*)(Qlp + qbase + 32);
    }

    // vo row into LDS
    for (int i = tid; i < Lseq; i += 256) vos[i] = vo[(size_t)bh * Lseq + i];

    // write tile 0
    *(f16x8*)&KhS[0][sr0][dw0] = nh0;
    *(f16x8*)&KhS[0][sr1][dw1] = nh1;
    *(f16x8*)&KlS[0][sr0][dw0] = nl0;
    *(f16x8*)&KlS[0][sr1][dw1] = nl1;
    __syncthreads();

    double Yd[2] = {0.0, 0.0}, Zd[2] = {0.0, 0.0};
    int i0 = (g * 8) ^ ((r & 7) << 3);

    for (int t = 0; t < NT; ++t) {
        int cur = t & 1;
        if (t + 1 < NT) {
            size_t kn = (size_t)(t + 1) * KT;
            nh0 = *(const f16x8*)(Kh_g + (kn + sr0) * Dm + so0);
            nh1 = *(const f16x8*)(Kh_g + (kn + sr1) * Dm + so1);
            nl0 = *(const f16x8*)(Kl_g + (kn + sr0) * Dm + so0);
            nl1 = *(const f16x8*)(Kl_g + (kn + sr1) * Dm + so1);
        }
        #pragma unroll
        for (int s = 0; s < 4; ++s) {
            int row = s * 16 + r;
            f16x8 ah0 = *(const f16x8*)&KhS[cur][row][i0];
            f16x8 ah1 = *(const f16x8*)&KhS[cur][row][i0 ^ 32];
            f16x8 al0 = *(const f16x8*)&KlS[cur][row][i0];
            f16x8 al1 = *(const f16x8*)&KlS[cur][row][i0 ^ 32];
            float4 vkv = *(const float4*)&vos[t * KT + s * 16 + g * 4];
            float vk[4] = {vkv.x, vkv.y, vkv.z, vkv.w};
            #pragma unroll
            for (int f = 0; f < 2; ++f) {
                f32x4 acc1 = {0.f, 0.f, 0.f, 0.f};
                f32x4 acc2 = {0.f, 0.f, 0.f, 0.f};
                acc1 = __builtin_amdgcn_mfma_f32_16x16x32_f16(ah0, Qh[f][0], acc1, 0, 0, 0);
                acc1 = __builtin_amdgcn_mfma_f32_16x16x32_f16(ah1, Qh[f][1], acc1, 0, 0, 0);
                acc2 = __builtin_amdgcn_mfma_f32_16x16x32_f16(ah0, Ql[f][0], acc2, 0, 0, 0);
                acc2 = __builtin_amdgcn_mfma_f32_16x16x32_f16(ah1, Ql[f][1], acc2, 0, 0, 0);
                acc2 = __builtin_amdgcn_mfma_f32_16x16x32_f16(al0, Qh[f][0], acc2, 0, 0, 0);
                acc2 = __builtin_amdgcn_mfma_f32_16x16x32_f16(al1, Qh[f][1], acc2, 0, 0, 0);
                float Ych = 0.f, Zch = 0.f;
                #pragma unroll
                for (int j = 0; j < 4; ++j) {
                    float sv = (acc1[j] + acc2[j] * (1.0f / 2048.0f)) * 0.125f;
                    float e = __expf(sv);
                    Ych += e * vk[j];
                    Zch += e;
                }
                Yd[f] += (double)Ych;
                Zd[f] += (double)Zch;
            }
        }
        if (t + 1 < NT) {
            int nxt = cur ^ 1;
            *(f16x8*)&KhS[nxt][sr0][dw0] = nh0;
            *(f16x8*)&KhS[nxt][sr1][dw1] = nh1;
            *(f16x8*)&KlS[nxt][sr0][dw0] = nl0;
            *(f16x8*)&KlS[nxt][sr1][dw1] = nl1;
        }
        __syncthreads();
    }

    #pragma unroll
    for (int f = 0; f < 2; ++f) {
        double Y = Yd[f], Z = Zd[f];
        Y += __shfl_xor(Y, 16, 64);
        Y += __shfl_xor(Y, 32, 64);
        Z += __shfl_xor(Z, 16, 64);
        Z += __shfl_xor(Z, 32, 64);
        if (lane < 16)
            blpart[(size_t)bh * Lseq + q0 + f * 16 + lane] = (float)(Y / Z);
    }
}

// ---------------- boundary logits -> hard bits (replicating reference fp path)
__global__ void blhard_kernel(const float* __restrict__ blpart, const float* __restrict__ u,
                              int* __restrict__ hard) {
    int i = blockIdx.x * 256 + threadIdx.x;   // b*L + l
    int b = i >> 11, l = i & (Lseq - 1);
    float bl = 0.f;
    #pragma unroll
    for (int h = 0; h < Hh; ++h)
        bl += blpart[((size_t)(b * Hh + h)) * Lseq + l];
    float x = bl + 1.0f;                       // + boundary_scores (== 1 exactly)
    float probs = 1.0f / (1.0f + expf(-x));
    probs = fminf(fmaxf(probs, 0.0f), 1.0f);
    float pl = logf(probs) - log1pf(-probs);
    float un = u[i];
    float noise = logf(un) - log1pf(-un);
    float t = pl + noise;
    float soft = 1.0f / (1.0f + expf(-t));
    hard[i] = (soft > 0.5f) ? 1 : 0;
}

// ---------------- per-batch scan: segment starts/ends + boundary count
__global__ void scan_kernel(const int* __restrict__ hard, int* __restrict__ segstart,
                            int* __restrict__ segend, int* __restrict__ kcount) {
    int b = blockIdx.x;
    int tid = threadIdx.x;
    __shared__ int hs[Lseq];
    __shared__ int chunk[256];
    for (int i = tid; i < Lseq; i += 256) {
        segstart[b * Lseq + i] = 0;
        segend[b * Lseq + i] = 0;
    }
    int base = b * Lseq;
    int sum = 0;
    int loc[8];
    #pragma unroll
    for (int j = 0; j < 8; ++j) {
        int v = hard[base + tid * 8 + j];
        hs[tid * 8 + j] = v;
        loc[j] = sum;
        sum += v;
    }
    chunk[tid] = sum;
    __syncthreads();
    for (int off = 1; off < 256; off <<= 1) {
        int v = (tid >= off) ? chunk[tid - off] : 0;
        __syncthreads();
        chunk[tid] += v;
        __syncthreads();
    }
    int ebase = chunk[tid] - sum;  // exclusive prefix of chunks
    #pragma unroll
    for (int j = 0; j < 8; ++j) {
        int ll = tid * 8 + j;
        int id = ebase + loc[j];
        if (ll == 0 || hs[ll - 1] == 1) segstart[b * Lseq + id] = ll;
        if (ll == Lseq - 1 || hs[ll] == 1) segend[b * Lseq + id] = ll + 1;
    }
    if (tid == 255) kcount[b] = chunk[255];
}

// ---------------- pooled[b,s,d] = mean of hidden over segment range (0 if empty)
__global__ void pool_kernel(const float* __restrict__ hidden, const int* __restrict__ segstart,
                            const int* __restrict__ segend, float* __restrict__ out) {
    int i = blockIdx.x * 256 + threadIdx.x;     // < B*L*D = 2^22
    int d = i & (Dm - 1);
    int s = (i >> 9) & (Lseq - 1);
    int b = i >> 20;
    int st = segstart[b * Lseq + s];
    int en = segend[b * Lseq + s];
    int n = en - st;
    float acc = 0.f;
    for (int l = st; l < en; ++l)
        acc += hidden[((size_t)b * Lseq + l) * Dm + d];
    out[i] = (n > 0) ? acc / (float)n : 0.0f;
}

// ---------------- binomial log-prob loss
__global__ void loss_kernel(const int* __restrict__ kcount, float* __restrict__ out) {
    if (threadIdx.x == 0 && blockIdx.x == 0) {
        float n = (float)Lseq;
        float acc = 0.f;
        for (int b = 0; b < Bsz; ++b) {
            float k = (float)kcount[b];
            float lp = lgammaf(n + 1.0f) - lgammaf(k + 1.0f) - lgammaf(n - k + 1.0f)
                     + k * logf(0.2f) + (n - k) * log1pf(-0.2f);
            acc += lp;
        }
        out[(size_t)Bsz * Lseq * Dm] = -(acc / (float)Bsz) / n;
    }
}

extern "C" void kernel_launch(void* const* d_in, const int* in_sizes, int n_in,
                              void* d_out, int out_size, void* d_ws, size_t ws_size,
                              hipStream_t stream) {
    const float* hidden = (const float*)d_in[0];
    const float* Wq = (const float*)d_in[1];
    const float* Wk = (const float*)d_in[2];
    const float* Wv = (const float*)d_in[3];
    const float* Wo = (const float*)d_in[4];
    const float* u  = (const float*)d_in[5];
    float* out = (float*)d_out;

    char* ws = (char*)d_ws;
    size_t off = 0;
    const size_t plane = (size_t)Bsz * Lseq * Dm * sizeof(_Float16);   // 8 MB
    _Float16* Qhp = (_Float16*)(ws + off); off += plane;
    _Float16* Qlp = (_Float16*)(ws + off); off += plane;
    _Float16* Khp = (_Float16*)(ws + off); off += plane;
    _Float16* Klp = (_Float16*)(ws + off); off += plane;
    float* Wvo = (float*)(ws + off); off += (size_t)Hh * Dm * 4;
    float* vo = (float*)(ws + off);  off += (size_t)Bsz * Hh * Lseq * 4;
    float* blpart = (float*)(ws + off); off += (size_t)Bsz * Hh * Lseq * 4;
    int* hard = (int*)(ws + off);    off += (size_t)Bsz * Lseq * 4;
    int* segstart = (int*)(ws + off); off += (size_t)Bsz * Lseq * 4;
    int* segend = (int*)(ws + off);  off += (size_t)Bsz * Lseq * 4;
    int* kcount = (int*)(ws + off);  off += 64;

    wvo_kernel<<<dim3(16), dim3(256), 0, stream>>>(Wv, Wo, Wvo);
    proj_qk_kernel<<<dim3(Dm / 64, (Bsz * Lseq) / 64), dim3(256), 0, stream>>>(
        hidden, Wq, Wk, Qhp, Qlp, Khp, Klp);
    vo_kernel<<<dim3(Bsz * Hh, Lseq / 256), dim3(256), 0, stream>>>(hidden, Wvo, vo);
    attn_mfma_kernel<<<dim3(32 * (Lseq / QBLK)), dim3(256), 0, stream>>>(
        Qhp, Qlp, Khp, Klp, vo, blpart);
    blhard_kernel<<<dim3((Bsz * Lseq) / 256), dim3(256), 0, stream>>>(blpart, u, hard);
    scan_kernel<<<dim3(Bsz), dim3(256), 0, stream>>>(hard, segstart, segend, kcount);
    pool_kernel<<<dim3((Bsz * Lseq * Dm) / 256), dim3(256), 0, stream>>>(hidden, segstart, segend, out);
    loss_kernel<<<dim3(1), dim3(64), 0, stream>>>(kcount, out);
}

// Round 4
// 148.030 us; speedup vs baseline: 4.2202x; 1.6574x over previous
//
#include <hip/hip_runtime.h>
#include <hip/hip_bf16.h>

#define Bsz 4
#define Lseq 2048
#define Dm 512
#define Hh 8
#define HD 64
#define QBLK 128
#define KT 64
#define NT (Lseq / KT)
#define PNT (Dm / 32)

typedef __attribute__((ext_vector_type(8))) _Float16 f16x8;
typedef __attribute__((ext_vector_type(4))) float f32x4;

// ---------------- Wvo fold: Wvo[h][c] = sum_d Wv[(h*64+d)*512 + c] * Wo[h*64+d]
__global__ void wvo_kernel(const float* __restrict__ Wv, const float* __restrict__ Wo,
                           float* __restrict__ Wvo) {
    int h = blockIdx.x >> 1;
    int c = (blockIdx.x & 1) * 256 + threadIdx.x;
    float acc = 0.f;
    #pragma unroll 8
    for (int d = 0; d < HD; ++d)
        acc += Wv[(size_t)(h * HD + d) * Dm + c] * Wo[h * HD + d];
    Wvo[h * Dm + c] = acc;
}

__device__ __forceinline__ void split8f(float4 x, float4 y, f16x8& h, f16x8& l) {
    float v[8] = {x.x, x.y, x.z, x.w, y.x, y.y, y.z, y.w};
    #pragma unroll
    for (int j = 0; j < 8; ++j) {
        _Float16 hh = (_Float16)v[j];
        h[j] = hh;
        l[j] = (_Float16)((v[j] - (float)hh) * 2048.0f);
    }
}

// ---------------- MFMA projection: C = hidden @ Wqk^T via f16x3 emulation.
// Combined weight rows [0,512)=Wq, [512,1024)=Wk. 128x128 tile, BK=32,
// 4 waves x (64x64), fp32->f16 hi/lo split done while staging into LDS.
// Epilogue emits hi/lo f16 planes for attention.
__global__ void __launch_bounds__(256, 2) proj_mfma_kernel(
    const float* __restrict__ A,
    const float* __restrict__ Wq, const float* __restrict__ Wk,
    _Float16* __restrict__ Qhp, _Float16* __restrict__ Qlp,
    _Float16* __restrict__ Khp, _Float16* __restrict__ Klp) {
    __shared__ _Float16 AhS[2][128][32];
    __shared__ _Float16 AlS[2][128][32];
    __shared__ _Float16 BhS[2][128][32];
    __shared__ _Float16 BlS[2][128][32];

    int tid = threadIdx.x;
    int lane = tid & 63, wid = tid >> 6;
    int wm = wid >> 1, wn = wid & 1;
    int r = lane & 15, g = lane >> 4;
    int m0 = blockIdx.x * 128;
    int nblk = blockIdx.y;
    bool isQ = nblk < 4;
    const float* Wsrc = isQ ? (Wq + (size_t)nblk * 128 * Dm)
                            : (Wk + (size_t)(nblk - 4) * 128 * Dm);
    _Float16* Hout = isQ ? Qhp : Khp;
    _Float16* Lout = isQ ? Qlp : Klp;
    int ncol0 = (nblk & 3) * 128;

    // staging chunk coords: 512 chunks (row 0..127, kchunk 0..3 of 8 floats)
    int c0 = tid * 2, c1 = tid * 2 + 1;
    int ar0 = c0 >> 2, akc0 = c0 & 3;
    int ar1 = c1 >> 2, akc1 = c1 & 3;
    int asw0 = (akc0 ^ ((ar0 >> 1) & 3)) * 8;
    int asw1 = (akc1 ^ ((ar1 >> 1) & 3)) * 8;

    const float* Abase = A + (size_t)m0 * Dm;

    float4 La0, La1, La2, La3, Lb0, Lb1, Lb2, Lb3;

#define PLOAD(T) do { \
    const float* ap0 = Abase + (size_t)ar0 * Dm + (T) * 32 + akc0 * 8; \
    const float* ap1 = Abase + (size_t)ar1 * Dm + (T) * 32 + akc1 * 8; \
    const float* bp0 = Wsrc + (size_t)ar0 * Dm + (T) * 32 + akc0 * 8; \
    const float* bp1 = Wsrc + (size_t)ar1 * Dm + (T) * 32 + akc1 * 8; \
    La0 = *(const float4*)ap0; La1 = *(const float4*)(ap0 + 4); \
    La2 = *(const float4*)ap1; La3 = *(const float4*)(ap1 + 4); \
    Lb0 = *(const float4*)bp0; Lb1 = *(const float4*)(bp0 + 4); \
    Lb2 = *(const float4*)bp1; Lb3 = *(const float4*)(bp1 + 4); \
} while (0)

#define PWRITE(BUF) do { \
    f16x8 hv, lv; \
    split8f(La0, La1, hv, lv); \
    *(f16x8*)&AhS[BUF][ar0][asw0] = hv; *(f16x8*)&AlS[BUF][ar0][asw0] = lv; \
    split8f(La2, La3, hv, lv); \
    *(f16x8*)&AhS[BUF][ar1][asw1] = hv; *(f16x8*)&AlS[BUF][ar1][asw1] = lv; \
    split8f(Lb0, Lb1, hv, lv); \
    *(f16x8*)&BhS[BUF][ar0][asw0] = hv; *(f16x8*)&BlS[BUF][ar0][asw0] = lv; \
    split8f(Lb2, Lb3, hv, lv); \
    *(f16x8*)&BhS[BUF][ar1][asw1] = hv; *(f16x8*)&BlS[BUF][ar1][asw1] = lv; \
} while (0)

    f32x4 acc1[4][4], acc2[4][4];
    #pragma unroll
    for (int mr = 0; mr < 4; ++mr)
        #pragma unroll
        for (int nr = 0; nr < 4; ++nr) {
            acc1[mr][nr] = (f32x4){0.f, 0.f, 0.f, 0.f};
            acc2[mr][nr] = (f32x4){0.f, 0.f, 0.f, 0.f};
        }

    PLOAD(0);
    PWRITE(0);
    __syncthreads();

    int sw8 = (g ^ ((r >> 1) & 3)) * 8;
    for (int t = 0; t < PNT; ++t) {
        int cur = t & 1;
        if (t + 1 < PNT) PLOAD(t + 1);
        f16x8 bhf[4], blf[4];
        #pragma unroll
        for (int nr = 0; nr < 4; ++nr) {
            int row = wn * 64 + nr * 16 + r;
            bhf[nr] = *(const f16x8*)&BhS[cur][row][sw8];
            blf[nr] = *(const f16x8*)&BlS[cur][row][sw8];
        }
        #pragma unroll
        for (int mr = 0; mr < 4; ++mr) {
            int row = wm * 64 + mr * 16 + r;
            f16x8 ah = *(const f16x8*)&AhS[cur][row][sw8];
            f16x8 al = *(const f16x8*)&AlS[cur][row][sw8];
            #pragma unroll
            for (int nr = 0; nr < 4; ++nr) {
                acc1[mr][nr] = __builtin_amdgcn_mfma_f32_16x16x32_f16(ah, bhf[nr], acc1[mr][nr], 0, 0, 0);
                acc2[mr][nr] = __builtin_amdgcn_mfma_f32_16x16x32_f16(ah, blf[nr], acc2[mr][nr], 0, 0, 0);
                acc2[mr][nr] = __builtin_amdgcn_mfma_f32_16x16x32_f16(al, bhf[nr], acc2[mr][nr], 0, 0, 0);
            }
        }
        if (t + 1 < PNT) PWRITE(cur ^ 1);
        __syncthreads();
    }

    #pragma unroll
    for (int mr = 0; mr < 4; ++mr)
        #pragma unroll
        for (int nr = 0; nr < 4; ++nr)
            #pragma unroll
            for (int j = 0; j < 4; ++j) {
                float C = acc1[mr][nr][j] + acc2[mr][nr][j] * (1.0f / 2048.0f);
                size_t m = (size_t)(m0 + wm * 64 + mr * 16 + g * 4 + j);
                size_t n = (size_t)(ncol0 + wn * 64 + nr * 16 + r);
                _Float16 hh = (_Float16)C;
                Hout[m * Dm + n] = hh;
                Lout[m * Dm + n] = (_Float16)((C - (float)hh) * 2048.0f);
            }
#undef PLOAD
#undef PWRITE
}

// ---------------- vo[b][h][l] = hidden[b,l,:] . Wvo[h,:]
__global__ void vo_kernel(const float* __restrict__ hidden, const float* __restrict__ Wvo,
                          float* __restrict__ vo) {
    int bh = blockIdx.x;           // 0..31
    int b = bh >> 3, h = bh & 7;
    int l = blockIdx.y * 256 + threadIdx.x;
    __shared__ float w[Dm];
    for (int i = threadIdx.x; i < Dm; i += 256) w[i] = Wvo[h * Dm + i];
    __syncthreads();
    const float* hr = hidden + ((size_t)b * Lseq + l) * Dm;
    float a0 = 0.f, a1 = 0.f, a2 = 0.f, a3 = 0.f;
    #pragma unroll 8
    for (int c = 0; c < Dm; c += 4) {
        float4 v = *(const float4*)(hr + c);
        a0 += v.x * w[c]; a1 += v.y * w[c + 1]; a2 += v.z * w[c + 2]; a3 += v.w * w[c + 3];
    }
    vo[(size_t)bh * Lseq + l] = (a0 + a1) + (a2 + a3);
}

// ---------------- MFMA attention, LDS-shared double-buffered K tiles.
__global__ void __launch_bounds__(256, 2) attn_mfma_kernel(
    const _Float16* __restrict__ Qhp, const _Float16* __restrict__ Qlp,
    const _Float16* __restrict__ Khp, const _Float16* __restrict__ Klp,
    const float* __restrict__ vo, float* __restrict__ blpart) {
    int tid = threadIdx.x;
    int wid = tid >> 6, lane = tid & 63;
    int blk = blockIdx.x;
    int bh = blk & 31;             // same-bh blocks -> same XCD (blk%8 = bh%8)
    int qblk = blk >> 5;           // 0..15
    int b = bh >> 3, h = bh & 7;
    int q0 = qblk * QBLK + wid * 32;
    int r = lane & 15, g = lane >> 4;

    __shared__ _Float16 KhS[2][KT][64];
    __shared__ _Float16 KlS[2][KT][64];
    __shared__ float vos[Lseq];

    const _Float16* Kh_g = Khp + ((size_t)b * Lseq) * Dm + h * HD;
    const _Float16* Kl_g = Klp + ((size_t)b * Lseq) * Dm + h * HD;

    // staging coords: 512 16B-chunks per plane, 2 per thread
    int c0 = tid * 2, c1 = tid * 2 + 1;
    int sr0 = c0 >> 3, so0 = (c0 & 7) * 8;
    int sr1 = c1 >> 3, so1 = (c1 & 7) * 8;
    int dw0 = (so0 ^ ((sr0 & 7) << 3));
    int dw1 = (so1 ^ ((sr1 & 7) << 3));

    // prologue: issue tile-0 loads
    f16x8 nh0 = *(const f16x8*)(Kh_g + (size_t)sr0 * Dm + so0);
    f16x8 nh1 = *(const f16x8*)(Kh_g + (size_t)sr1 * Dm + so1);
    f16x8 nl0 = *(const f16x8*)(Kl_g + (size_t)sr0 * Dm + so0);
    f16x8 nl1 = *(const f16x8*)(Kl_g + (size_t)sr1 * Dm + so1);

    // Q fragments (2 per wave)
    f16x8 Qh[2][2], Ql[2][2];
    #pragma unroll
    for (int f = 0; f < 2; ++f) {
        size_t qbase = ((size_t)(b * Lseq + q0 + f * 16 + r)) * Dm + h * HD + g * 8;
        Qh[f][0] = *(const f16x8*)(Qhp + qbase);
        Qh[f][1] = *(const f16x8*)(Qhp + qbase + 32);
        Ql[f][0] = *(const f16x8*)(Qlp + qbase);
        Ql[f][1] = *(const f16x8*)(Qlp + qbase + 32);
    }

    // vo row into LDS
    for (int i = tid; i < Lseq; i += 256) vos[i] = vo[(size_t)bh * Lseq + i];

    // write tile 0
    *(f16x8*)&KhS[0][sr0][dw0] = nh0;
    *(f16x8*)&KhS[0][sr1][dw1] = nh1;
    *(f16x8*)&KlS[0][sr0][dw0] = nl0;
    *(f16x8*)&KlS[0][sr1][dw1] = nl1;
    __syncthreads();

    double Yd[2] = {0.0, 0.0}, Zd[2] = {0.0, 0.0};
    int i0 = (g * 8) ^ ((r & 7) << 3);

    for (int t = 0; t < NT; ++t) {
        int cur = t & 1;
        if (t + 1 < NT) {
            size_t kn = (size_t)(t + 1) * KT;
            nh0 = *(const f16x8*)(Kh_g + (kn + sr0) * Dm + so0);
            nh1 = *(const f16x8*)(Kh_g + (kn + sr1) * Dm + so1);
            nl0 = *(const f16x8*)(Kl_g + (kn + sr0) * Dm + so0);
            nl1 = *(const f16x8*)(Kl_g + (kn + sr1) * Dm + so1);
        }
        #pragma unroll
        for (int s = 0; s < 4; ++s) {
            int row = s * 16 + r;
            f16x8 ah0 = *(const f16x8*)&KhS[cur][row][i0];
            f16x8 ah1 = *(const f16x8*)&KhS[cur][row][i0 ^ 32];
            f16x8 al0 = *(const f16x8*)&KlS[cur][row][i0];
            f16x8 al1 = *(const f16x8*)&KlS[cur][row][i0 ^ 32];
            float4 vkv = *(const float4*)&vos[t * KT + s * 16 + g * 4];
            float vk[4] = {vkv.x, vkv.y, vkv.z, vkv.w};
            #pragma unroll
            for (int f = 0; f < 2; ++f) {
                f32x4 acc1 = {0.f, 0.f, 0.f, 0.f};
                f32x4 acc2 = {0.f, 0.f, 0.f, 0.f};
                acc1 = __builtin_amdgcn_mfma_f32_16x16x32_f16(ah0, Qh[f][0], acc1, 0, 0, 0);
                acc1 = __builtin_amdgcn_mfma_f32_16x16x32_f16(ah1, Qh[f][1], acc1, 0, 0, 0);
                acc2 = __builtin_amdgcn_mfma_f32_16x16x32_f16(ah0, Ql[f][0], acc2, 0, 0, 0);
                acc2 = __builtin_amdgcn_mfma_f32_16x16x32_f16(ah1, Ql[f][1], acc2, 0, 0, 0);
                acc2 = __builtin_amdgcn_mfma_f32_16x16x32_f16(al0, Qh[f][0], acc2, 0, 0, 0);
                acc2 = __builtin_amdgcn_mfma_f32_16x16x32_f16(al1, Qh[f][1], acc2, 0, 0, 0);
                float Ych = 0.f, Zch = 0.f;
                #pragma unroll
                for (int j = 0; j < 4; ++j) {
                    float sv = (acc1[j] + acc2[j] * (1.0f / 2048.0f)) * 0.125f;
                    float e = __expf(sv);
                    Ych += e * vk[j];
                    Zch += e;
                }
                Yd[f] += (double)Ych;
                Zd[f] += (double)Zch;
            }
        }
        if (t + 1 < NT) {
            int nxt = cur ^ 1;
            *(f16x8*)&KhS[nxt][sr0][dw0] = nh0;
            *(f16x8*)&KhS[nxt][sr1][dw1] = nh1;
            *(f16x8*)&KlS[nxt][sr0][dw0] = nl0;
            *(f16x8*)&KlS[nxt][sr1][dw1] = nl1;
        }
        __syncthreads();
    }

    #pragma unroll
    for (int f = 0; f < 2; ++f) {
        double Y = Yd[f], Z = Zd[f];
        Y += __shfl_xor(Y, 16, 64);
        Y += __shfl_xor(Y, 32, 64);
        Z += __shfl_xor(Z, 16, 64);
        Z += __shfl_xor(Z, 32, 64);
        if (lane < 16)
            blpart[(size_t)bh * Lseq + q0 + f * 16 + lane] = (float)(Y / Z);
    }
}

// ---------------- boundary logits -> hard bits (replicating reference fp path)
__global__ void blhard_kernel(const float* __restrict__ blpart, const float* __restrict__ u,
                              int* __restrict__ hard) {
    int i = blockIdx.x * 256 + threadIdx.x;   // b*L + l
    int b = i >> 11, l = i & (Lseq - 1);
    float bl = 0.f;
    #pragma unroll
    for (int h = 0; h < Hh; ++h)
        bl += blpart[((size_t)(b * Hh + h)) * Lseq + l];
    float x = bl + 1.0f;                       // + boundary_scores (== 1 exactly)
    float probs = 1.0f / (1.0f + expf(-x));
    probs = fminf(fmaxf(probs, 0.0f), 1.0f);
    float pl = logf(probs) - log1pf(-probs);
    float un = u[i];
    float noise = logf(un) - log1pf(-un);
    float t = pl + noise;
    float soft = 1.0f / (1.0f + expf(-t));
    hard[i] = (soft > 0.5f) ? 1 : 0;
}

// ---------------- per-batch scan: segment starts/ends + boundary count
__global__ void scan_kernel(const int* __restrict__ hard, int* __restrict__ segstart,
                            int* __restrict__ segend, int* __restrict__ kcount) {
    int b = blockIdx.x;
    int tid = threadIdx.x;
    __shared__ int hs[Lseq];
    __shared__ int chunk[256];
    for (int i = tid; i < Lseq; i += 256) {
        segstart[b * Lseq + i] = 0;
        segend[b * Lseq + i] = 0;
    }
    int base = b * Lseq;
    int sum = 0;
    int loc[8];
    #pragma unroll
    for (int j = 0; j < 8; ++j) {
        int v = hard[base + tid * 8 + j];
        hs[tid * 8 + j] = v;
        loc[j] = sum;
        sum += v;
    }
    chunk[tid] = sum;
    __syncthreads();
    for (int off = 1; off < 256; off <<= 1) {
        int v = (tid >= off) ? chunk[tid - off] : 0;
        __syncthreads();
        chunk[tid] += v;
        __syncthreads();
    }
    int ebase = chunk[tid] - sum;  // exclusive prefix of chunks
    #pragma unroll
    for (int j = 0; j < 8; ++j) {
        int ll = tid * 8 + j;
        int id = ebase + loc[j];
        if (ll == 0 || hs[ll - 1] == 1) segstart[b * Lseq + id] = ll;
        if (ll == Lseq - 1 || hs[ll] == 1) segend[b * Lseq + id] = ll + 1;
    }
    if (tid == 255) kcount[b] = chunk[255];
}

// ---------------- pooled[b,s,d] = mean of hidden over segment range (0 if empty)
__global__ void pool_kernel(const float* __restrict__ hidden, const int* __restrict__ segstart,
                            const int* __restrict__ segend, float* __restrict__ out) {
    int i = blockIdx.x * 256 + threadIdx.x;     // < B*L*D = 2^22
    int d = i & (Dm - 1);
    int s = (i >> 9) & (Lseq - 1);
    int b = i >> 20;
    int st = segstart[b * Lseq + s];
    int en = segend[b * Lseq + s];
    int n = en - st;
    float acc = 0.f;
    for (int l = st; l < en; ++l)
        acc += hidden[((size_t)b * Lseq + l) * Dm + d];
    out[i] = (n > 0) ? acc / (float)n : 0.0f;
}

// ---------------- binomial log-prob loss
__global__ void loss_kernel(const int* __restrict__ kcount, float* __restrict__ out) {
    if (threadIdx.x == 0 && blockIdx.x == 0) {
        float n = (float)Lseq;
        float acc = 0.f;
        for (int b = 0; b < Bsz; ++b) {
            float k = (float)kcount[b];
            float lp = lgammaf(n + 1.0f) - lgammaf(k + 1.0f) - lgammaf(n - k + 1.0f)
                     + k * logf(0.2f) + (n - k) * log1pf(-0.2f);
            acc += lp;
        }
        out[(size_t)Bsz * Lseq * Dm] = -(acc / (float)Bsz) / n;
    }
}

extern "C" void kernel_launch(void* const* d_in, const int* in_sizes, int n_in,
                              void* d_out, int out_size, void* d_ws, size_t ws_size,
                              hipStream_t stream) {
    const float* hidden = (const float*)d_in[0];
    const float* Wq = (const float*)d_in[1];
    const float* Wk = (const float*)d_in[2];
    const float* Wv = (const float*)d_in[3];
    const float* Wo = (const float*)d_in[4];
    const float* u  = (const float*)d_in[5];
    float* out = (float*)d_out;

    char* ws = (char*)d_ws;
    size_t off = 0;
    const size_t plane = (size_t)Bsz * Lseq * Dm * sizeof(_Float16);   // 8 MB
    _Float16* Qhp = (_Float16*)(ws + off); off += plane;
    _Float16* Qlp = (_Float16*)(ws + off); off += plane;
    _Float16* Khp = (_Float16*)(ws + off); off += plane;
    _Float16* Klp = (_Float16*)(ws + off); off += plane;
    float* Wvo = (float*)(ws + off); off += (size_t)Hh * Dm * 4;
    float* vo = (float*)(ws + off);  off += (size_t)Bsz * Hh * Lseq * 4;
    float* blpart = (float*)(ws + off); off += (size_t)Bsz * Hh * Lseq * 4;
    int* hard = (int*)(ws + off);    off += (size_t)Bsz * Lseq * 4;
    int* segstart = (int*)(ws + off); off += (size_t)Bsz * Lseq * 4;
    int* segend = (int*)(ws + off);  off += (size_t)Bsz * Lseq * 4;
    int* kcount = (int*)(ws + off);  off += 64;

    wvo_kernel<<<dim3(16), dim3(256), 0, stream>>>(Wv, Wo, Wvo);
    proj_mfma_kernel<<<dim3((Bsz * Lseq) / 128, 8), dim3(256), 0, stream>>>(
        hidden, Wq, Wk, Qhp, Qlp, Khp, Klp);
    vo_kernel<<<dim3(Bsz * Hh, Lseq / 256), dim3(256), 0, stream>>>(hidden, Wvo, vo);
    attn_mfma_kernel<<<dim3(32 * (Lseq / QBLK)), dim3(256), 0, stream>>>(
        Qhp, Qlp, Khp, Klp, vo, blpart);
    blhard_kernel<<<dim3((Bsz * Lseq) / 256), dim3(256), 0, stream>>>(blpart, u, hard);
    scan_kernel<<<dim3(Bsz), dim3(256), 0, stream>>>(hard, segstart, segend, kcount);
    pool_kernel<<<dim3((Bsz * Lseq * Dm) / 256), dim3(256), 0, stream>>>(hidden, segstart, segend, out);
    loss_kernel<<<dim3(1), dim3(64), 0, stream>>>(kcount, out);
}